// Round 1
// baseline (7558.390 us; speedup 1.0000x reference)
//
#include <hip/hip_runtime.h>
#include <hip/hip_bf16.h>
#include <stdint.h>

// ---------------------------------------------------------------------------
// CrossEntropyLoss: loss = lw/chunk * sum_rows( logsumexp_v(h_i . W_v) - h_i . W_label )
// M=8192 rows, K=2048, V=128000.  Strategy: bf16 MFMA GEMM (m97 structure) with
// fused exp+row-sum epilogue; exact f32 target dot; final scalar reduce.
// ---------------------------------------------------------------------------

typedef __attribute__((ext_vector_type(8))) __bf16 bf16x8;
typedef __attribute__((ext_vector_type(4))) float f32x4;

__device__ __forceinline__ unsigned int pack2_bf16_rne(float lo, float hi) {
    unsigned int ulo = __float_as_uint(lo);
    ulo += 0x7fffu + ((ulo >> 16) & 1u);
    unsigned int uhi = __float_as_uint(hi);
    uhi += 0x7fffu + ((uhi >> 16) & 1u);
    return (ulo >> 16) | (uhi & 0xffff0000u);
}

// Convert n8*8 floats -> bf16 (packed), 8 elements per thread, 16B stores.
__global__ void cvt_f32_bf16(const float* __restrict__ src,
                             unsigned int* __restrict__ dst, long long n8) {
    long long i = (long long)blockIdx.x * blockDim.x + threadIdx.x;
    if (i >= n8) return;
    const float4* s4 = (const float4*)src;
    float4 a = s4[i * 2];
    float4 b = s4[i * 2 + 1];
    uint4 o;
    o.x = pack2_bf16_rne(a.x, a.y);
    o.y = pack2_bf16_rne(a.z, a.w);
    o.z = pack2_bf16_rne(b.x, b.y);
    o.w = pack2_bf16_rne(b.z, b.w);
    ((uint4*)dst)[i] = o;
}

// ---------------------------------------------------------------------------
// GEMM + exp + row-sum epilogue.
// A: [M][K] bf16 (hidden), Bs: [ntiles*128][K] bf16 (W slice, row-major over K).
// Block = 256 threads = 4 waves (2x2), tile 128x128, BK=64.
// blockIdx.x = bn * Mtiles + bm  (consecutive blocks share the same W tile).
// ---------------------------------------------------------------------------
#define BK 64

__global__ __launch_bounds__(256) void gemm_sumexp(
    const unsigned short* __restrict__ A,
    const unsigned short* __restrict__ Bs,
    float* __restrict__ rowsum,
    int K, int Mtiles)
{
    __shared__ unsigned short sA[128 * BK];
    __shared__ unsigned short sB[128 * BK];

    const int t = threadIdx.x;
    const int lane = t & 63;
    const int w = t >> 6;        // wave id 0..3
    const int wm = w & 1;        // wave row (2x2 wave grid)
    const int wn = w >> 1;       // wave col

    const int bm = blockIdx.x % Mtiles;
    const int bn = blockIdx.x / Mtiles;

    const unsigned short* Ab = A + (size_t)bm * 128 * K;
    const unsigned short* Bb = Bs + (size_t)bn * 128 * K;

    f32x4 zero = {0.f, 0.f, 0.f, 0.f};
    f32x4 acc[4][4];
#pragma unroll
    for (int i = 0; i < 4; ++i)
#pragma unroll
        for (int j = 0; j < 4; ++j) acc[i][j] = zero;

    // staging geometry: chunk = (w*4 + r), 1024B per chunk; lane covers 16B.
    const int stage_row = w * 32 + (lane >> 3);  // + r*8
    const int stage_col = (lane & 7) * 8;        // bf16 elements

    for (int kt = 0; kt < K; kt += BK) {
#pragma unroll
        for (int r = 0; r < 4; ++r) {
            __builtin_amdgcn_global_load_lds(
                (__attribute__((address_space(1))) void*)(Ab + (size_t)(stage_row + r * 8) * K + kt + stage_col),
                (__attribute__((address_space(3))) void*)(&sA[(w * 4 + r) * 512]),
                16, 0, 0);
        }
#pragma unroll
        for (int r = 0; r < 4; ++r) {
            __builtin_amdgcn_global_load_lds(
                (__attribute__((address_space(1))) void*)(Bb + (size_t)(stage_row + r * 8) * K + kt + stage_col),
                (__attribute__((address_space(3))) void*)(&sB[(w * 4 + r) * 512]),
                16, 0, 0);
        }
        __syncthreads();

#pragma unroll
        for (int kk = 0; kk < 2; ++kk) {
            const int kidx = kk * 32 + (lane >> 4) * 8;
            bf16x8 af[4], bfr[4];
#pragma unroll
            for (int mf = 0; mf < 4; ++mf) {
                int row = wm * 64 + mf * 16 + (lane & 15);
                af[mf] = *(const bf16x8*)&sA[row * BK + kidx];
            }
#pragma unroll
            for (int nf = 0; nf < 4; ++nf) {
                int row = wn * 64 + nf * 16 + (lane & 15);
                bfr[nf] = *(const bf16x8*)&sB[row * BK + kidx];
            }
#pragma unroll
            for (int mf = 0; mf < 4; ++mf)
#pragma unroll
                for (int nf = 0; nf < 4; ++nf)
                    acc[mf][nf] = __builtin_amdgcn_mfma_f32_16x16x32_bf16(
                        af[mf], bfr[nf], acc[mf][nf], 0, 0, 0);
        }
        __syncthreads();
    }

    // Epilogue: C/D layout (16x16): col = lane&15, row = (lane>>4)*4 + reg.
    // sum exp over this block's 128 columns per row, atomicAdd into rowsum.
    float s[4][4];
#pragma unroll
    for (int mf = 0; mf < 4; ++mf) {
#pragma unroll
        for (int j = 0; j < 4; ++j) {
            float v = 0.f;
#pragma unroll
            for (int nf = 0; nf < 4; ++nf) v += __expf(acc[mf][nf][j]);
#pragma unroll
            for (int off = 1; off < 16; off <<= 1) v += __shfl_xor(v, off, 64);
            s[mf][j] = v;
        }
    }
    if ((lane & 15) == 0) {
        const int g = lane >> 4;
        const int rowbase = bm * 128 + wm * 64 + g * 4;
#pragma unroll
        for (int mf = 0; mf < 4; ++mf)
#pragma unroll
            for (int j = 0; j < 4; ++j)
                atomicAdd(&rowsum[rowbase + mf * 16 + j], s[mf][j]);
    }
}

// Exact f32 target logit: one block per row.
__global__ void tgt_kernel(const float* __restrict__ h, const float* __restrict__ W,
                           const int* __restrict__ labels, float* __restrict__ tgt, int D) {
    const int row = blockIdx.x;
    const int lab = labels[row];
    const float4* hr = (const float4*)(h + (size_t)row * D);
    const float4* wr = (const float4*)(W + (size_t)lab * D);
    float p = 0.f;
    for (int i = threadIdx.x; i < D / 4; i += blockDim.x) {
        float4 a = hr[i], b = wr[i];
        p += a.x * b.x + a.y * b.y + a.z * b.z + a.w * b.w;
    }
#pragma unroll
    for (int off = 32; off; off >>= 1) p += __shfl_xor(p, off, 64);
    __shared__ float red[4];
    if ((threadIdx.x & 63) == 0) red[threadIdx.x >> 6] = p;
    __syncthreads();
    if (threadIdx.x == 0) tgt[row] = red[0] + red[1] + red[2] + red[3];
}

__global__ void final_kernel(const float* __restrict__ rowsum, const float* __restrict__ tgt,
                             const float* __restrict__ lw, const int* __restrict__ csz,
                             float* __restrict__ out, int M) {
    float p = 0.f;
    for (int i = threadIdx.x; i < M; i += blockDim.x)
        p += logf(rowsum[i]) - tgt[i];
#pragma unroll
    for (int off = 32; off; off >>= 1) p += __shfl_xor(p, off, 64);
    __shared__ float red[4];
    if ((threadIdx.x & 63) == 0) red[threadIdx.x >> 6] = p;
    __syncthreads();
    if (threadIdx.x == 0) out[0] = lw[0] * (red[0] + red[1] + red[2] + red[3]) / (float)csz[0];
}

extern "C" void kernel_launch(void* const* d_in, const int* in_sizes, int n_in,
                              void* d_out, int out_size, void* d_ws, size_t ws_size,
                              hipStream_t stream) {
    const float* h = (const float*)d_in[0];       // [M][D] f32
    const float* W = (const float*)d_in[1];       // [V][D] f32
    const int* labels = (const int*)d_in[2];      // [M]
    const float* lw = (const float*)d_in[3];      // scalar
    const int* csz = (const int*)d_in[4];         // scalar (1024)

    const int M = in_sizes[2];                    // 8192
    const int D = in_sizes[0] / M;                // 2048
    const int V = in_sizes[1] / D;                // 128000
    const int Mtiles = M / 128;                   // 64
    const int total_vtiles = V / 128;             // 1000

    char* ws = (char*)d_ws;
    float* rowsum = (float*)ws;                                   // M floats
    float* tgt = (float*)(ws + (size_t)M * 4);                    // M floats
    unsigned short* Abf = (unsigned short*)(ws + (size_t)M * 8);  // M*D bf16
    size_t Abytes = (size_t)M * D * 2;
    unsigned short* Wbf = (unsigned short*)(ws + (size_t)M * 8 + Abytes);

    const size_t tile_bytes = (size_t)128 * D * 2;  // 512 KB per vocab tile
    long long avail = (long long)ws_size - (long long)((size_t)M * 8 + Abytes);
    int slice_tiles = (avail > 0) ? (int)(avail / (long long)tile_bytes) : 1;
    if (slice_tiles > total_vtiles) slice_tiles = total_vtiles;
    if (slice_tiles < 1) slice_tiles = 1;

    // zero rowsum + tgt
    hipMemsetAsync(rowsum, 0, (size_t)M * 8, stream);

    // convert hidden -> bf16
    long long nA8 = (long long)M * D / 8;
    cvt_f32_bf16<<<(unsigned)((nA8 + 255) / 256), 256, 0, stream>>>(h, (unsigned int*)Abf, nA8);

    // per-slice: convert W slice -> bf16, then GEMM+exp-accumulate
    for (int t0 = 0; t0 < total_vtiles; t0 += slice_tiles) {
        int nt = slice_tiles;
        if (t0 + nt > total_vtiles) nt = total_vtiles - t0;
        long long nW8 = (long long)nt * 128 * D / 8;
        cvt_f32_bf16<<<(unsigned)((nW8 + 255) / 256), 256, 0, stream>>>(
            W + (size_t)t0 * 128 * D, (unsigned int*)Wbf, nW8);
        gemm_sumexp<<<(unsigned)(Mtiles * nt), 256, 0, stream>>>(Abf, Wbf, rowsum, D, Mtiles);
    }

    tgt_kernel<<<M, 256, 0, stream>>>(h, W, labels, tgt, D);
    final_kernel<<<1, 256, 0, stream>>>(rowsum, tgt, lw, csz, (float*)d_out, M);
}